// Round 7
// baseline (748.274 us; speedup 1.0000x reference)
//
#include <hip/hip_runtime.h>

#define B_TOT 2048
#define M_SEQ 64
#define SDIM 32
#define CDIM 8
#define LDIM 128
#define HDIM 512

#define NROWS_NEXT (B_TOT * M_SEQ)       // 131072
#define NROWS_ALL  (NROWS_NEXT + B_TOT)  // 133120

typedef short bf16x8 __attribute__((ext_vector_type(8)));
typedef float f32x16 __attribute__((ext_vector_type(16)));
typedef float f32x4v __attribute__((ext_vector_type(4)));

__device__ __forceinline__ unsigned short f2bf(float f) {
    unsigned int u = __builtin_bit_cast(unsigned int, f);
    u = u + 0x7FFFu + ((u >> 16) & 1u);   // round-to-nearest-even
    return (unsigned short)(u >> 16);
}

// bf16 h-buffer swizzle (1024B rows): XOR bits 4-7 with row&15. Bijective,
// 16B-block preserving; applied to the FULL byte address (add-then-xor).
__device__ __forceinline__ unsigned swzh(unsigned b) { return b ^ (((b >> 10) & 15u) << 4); }
// fp32 staging tile swizzle (512B rows)
__device__ __forceinline__ unsigned swzf(unsigned b) { return b ^ (((b >> 9) & 15u) << 4); }

// ---------------------------------------------------------------------------
// Pack fp32 W[K][N] -> bf16 fragment-major for 32x32x16 MFMA B-operand:
// out[((kt*CT + ct)*64 + lane)*8 + j] = W[kt*16 + (lane>>5)*8 + j][ct*32 + (lane&31)]
// ---------------------------------------------------------------------------
__device__ __forceinline__ void pack_one(const float* __restrict__ W, short* __restrict__ out,
                                         int e, int N, int CT) {
    int j    = e & 7;
    int lane = (e >> 3) & 63;
    int tile = e >> 9;
    int ct   = tile % CT;
    int kt   = tile / CT;
    int k = kt * 16 + ((lane >> 5) << 3) + j;
    int n = (ct << 5) + (lane & 31);
    out[e] = (short)f2bf(W[(size_t)k * N + n]);
}

#define P_S0 16384
#define P_S1 (P_S0 + 262144)
#define P_S2 (P_S1 + 262144)
#define P_S3 (P_S2 + 65536)   // 606208 total

__global__ void pack_all(const float* __restrict__ w0, const float* __restrict__ w1,
                         const float* __restrict__ w2, const float* __restrict__ w3,
                         short* __restrict__ o0, short* __restrict__ o1,
                         short* __restrict__ o2, short* __restrict__ o3) {
    int id = blockIdx.x * 256 + threadIdx.x;
    if (id < P_S0)      pack_one(w0, o0, id, HDIM, 16);
    else if (id < P_S1) pack_one(w1, o1, id - P_S0, HDIM, 16);
    else if (id < P_S2) pack_one(w2, o2, id - P_S1, HDIM, 16);
    else if (id < P_S3) pack_one(w3, o3, id - P_S2, LDIM, 4);
}

// ---------------------------------------------------------------------------
// One 512-out MLP layer over a 64-row tile, in-place in 64KB LDS h-buffer.
// 8 waves = 2 row-tiles x 4 col-groups; wave (rt,cg) owns rows rt*32..+31 and
// col-tiles cg*4..cg*4+3. Per kt: ONE ds_read_b128 (A) feeds FOUR MFMAs
// (LDS:MFMA pipe ratio 192:128 per CU, was 384:128). A and B 1-kt prefetched.
// ---------------------------------------------------------------------------
template<int KT>
__device__ __forceinline__ void layer32(char* hbuf, const short* __restrict__ pb,
                                        const float* __restrict__ bias,
                                        int rt, int cg, int lane) {
    const int l31   = lane & 31;
    const int lhalf = lane >> 5;
    const unsigned rowbase = (unsigned)(rt * 32768 + l31 * 1024 + (lhalf << 4));
    const unsigned xmask   = ((unsigned)(lane & 15)) << 4;

    f32x16 acc[4];
    #pragma unroll
    for (int i = 0; i < 4; ++i)
        #pragma unroll
        for (int r = 0; r < 16; ++r) acc[i][r] = 0.f;

    const short* pB = pb + ((cg * 4) << 9) + (lane << 3);   // kt stride = 16*512 = 8192

    bf16x8 a = *(const bf16x8*)(hbuf + (rowbase ^ xmask));
    bf16x8 bc[4];
    #pragma unroll
    for (int i = 0; i < 4; ++i) bc[i] = *(const bf16x8*)(pB + (i << 9));

    #pragma unroll
    for (int kt = 0; kt < KT; ++kt) {
        const int ktn = (kt + 1 < KT) ? kt + 1 : kt;
        bf16x8 an = *(const bf16x8*)(hbuf + ((rowbase + (unsigned)ktn * 32u) ^ xmask));
        bf16x8 bn[4];
        #pragma unroll
        for (int i = 0; i < 4; ++i) bn[i] = *(const bf16x8*)(pB + ktn * 8192 + (i << 9));
        #pragma unroll
        for (int i = 0; i < 4; ++i)
            acc[i] = __builtin_amdgcn_mfma_f32_32x32x16_bf16(a, bc[i], acc[i], 0, 0, 0);
        a = an;
        #pragma unroll
        for (int i = 0; i < 4; ++i) bc[i] = bn[i];
    }
    __syncthreads();   // all reads of hbuf done before in-place overwrite

    // epilogue: bias + relu + bf16 back into hbuf.
    // C/D layout (m74/m101): col=lane&31, row=(reg&3)+8*(reg>>2)+4*(lane>>5)
    #pragma unroll
    for (int i = 0; i < 4; ++i) {
        int colg = (cg * 4 + i) * 32 + l31;
        float bv = bias[colg];
        #pragma unroll
        for (int reg = 0; reg < 16; ++reg) {
            int row = rt * 32 + (reg & 3) + 8 * (reg >> 2) + 4 * lhalf;
            float v = fmaxf(acc[i][reg] + bv, 0.f);
            *(unsigned short*)(hbuf + swzh((unsigned)(row * 1024 + colg * 2))) = f2bf(v);
        }
    }
    __syncthreads();
}

// ---------------------------------------------------------------------------
// Fused encoder: 64 rows/block, 512 threads, 64KB LDS (2 blocks/CU).
// Blocks 0..2047 -> x_next rows; 2048..2079 -> x_k rows.
// ---------------------------------------------------------------------------
__global__ __launch_bounds__(512, 4) void encoder_kernel(
    const float* __restrict__ x_next, const float* __restrict__ x_k,
    const short* __restrict__ pw0, const short* __restrict__ pw1,
    const short* __restrict__ pw2, const short* __restrict__ pw3,
    const float* __restrict__ b0, const float* __restrict__ b1,
    const float* __restrict__ b2, const float* __restrict__ b3,
    float* __restrict__ z_target, float* __restrict__ z_k_out) {
    __shared__ __attribute__((aligned(16))) char hbuf[64 * 1024];
    const int tid   = threadIdx.x;
    const int wave  = tid >> 6;
    const int lane  = tid & 63;
    const int l31   = lane & 31;
    const int lhalf = lane >> 5;
    const int rt    = wave >> 2;     // 0..1
    const int cg    = wave & 3;      // 0..3
    const int r0    = blockIdx.x * 64;

    const float* xin;
    float* zout;
    bool is_tgt = (r0 < NROWS_NEXT);
    if (is_tgt) {
        xin  = x_next + (size_t)r0 * SDIM;
        zout = z_target + (size_t)r0 * LDIM;
    } else {
        xin  = x_k + (size_t)(r0 - NROWS_NEXT) * SDIM;
        zout = z_k_out + (size_t)(r0 - NROWS_NEXT) * LDIM;
    }

    // stage 64x32 fp32 -> bf16 into h cols [0,32)
    {
        int row = tid >> 3;
        int c   = (tid & 7) * 4;
        float4 v = *(const float4*)(xin + row * SDIM + c);
        uint2 pk;
        pk.x = (unsigned int)f2bf(v.x) | ((unsigned int)f2bf(v.y) << 16);
        pk.y = (unsigned int)f2bf(v.z) | ((unsigned int)f2bf(v.w) << 16);
        *(uint2*)(hbuf + swzh((unsigned)(row * 1024 + c * 2))) = pk;
    }
    __syncthreads();

    layer32<2>(hbuf, pw0, b0, rt, cg, lane);    // 32  -> 512, relu
    layer32<32>(hbuf, pw1, b1, rt, cg, lane);   // 512 -> 512, relu
    layer32<32>(hbuf, pw2, b2, rt, cg, lane);   // 512 -> 512, relu

    // layer 3: 512 -> 128, no relu. Wave (rt,cg): col-tile cg, rows rt*32..+31.
    {
        const unsigned rowbase = (unsigned)(rt * 32768 + l31 * 1024 + (lhalf << 4));
        const unsigned xmask   = ((unsigned)(lane & 15)) << 4;
        f32x16 acc;
        #pragma unroll
        for (int i = 0; i < 16; ++i) acc[i] = 0.f;

        const short* pB = pw3 + (cg << 9) + (lane << 3);    // kt stride = 4*512 = 2048
        bf16x8 a = *(const bf16x8*)(hbuf + (rowbase ^ xmask));
        bf16x8 b = *(const bf16x8*)(pB);
        #pragma unroll
        for (int kt = 0; kt < 32; ++kt) {
            const int ktn = (kt < 31) ? kt + 1 : kt;
            bf16x8 an = *(const bf16x8*)(hbuf + ((rowbase + (unsigned)ktn * 32u) ^ xmask));
            bf16x8 bn = *(const bf16x8*)(pB + ktn * 2048);
            acc = __builtin_amdgcn_mfma_f32_32x32x16_bf16(a, b, acc, 0, 0, 0);
            a = an; b = bn;
        }
        __syncthreads();   // done reading bf16 h; reuse hbuf as fp32 [64][128]

        int colg = cg * 32 + l31;
        float bv = b3[colg];
        #pragma unroll
        for (int reg = 0; reg < 16; ++reg) {
            int row = rt * 32 + (reg & 3) + 8 * (reg >> 2) + 4 * lhalf;
            *(float*)(hbuf + swzf((unsigned)(row * 512 + colg * 4))) = acc[reg] + bv;
        }
        __syncthreads();

        #pragma unroll
        for (int pass = 0; pass < 4; ++pass) {
            unsigned L = (unsigned)(pass * 512 + tid) * 16;
            f32x4v v = *(const f32x4v*)(hbuf + swzf(L));
            if (is_tgt) __builtin_nontemporal_store(v, (f32x4v*)(zout + (L >> 2)));
            else        *(f32x4v*)(zout + (L >> 2)) = v;
        }
    }
}

// ---------------------------------------------------------------------------
// Recurrence — VERBATIM round-3 version (known-good: other=163us aggregate).
// 512 blocks x 512 threads; block owns 4 batch rows. Thread t: out-col t&127,
// K-slice (t>>7)*32 of A_w in 32 regs. Cross-slice reduce via LDS.
// ---------------------------------------------------------------------------
#define RROWS 4
__global__ __launch_bounds__(512) void recurrence_kernel(
    const float* __restrict__ zk, const float* __restrict__ u,
    const float* __restrict__ Bw, const float* __restrict__ Aw,
    float* __restrict__ zpred) {
    __shared__ float z_lds[RROWS][128];
    __shared__ float part[4][RROWS][128];
    __shared__ float Bw_lds[CDIM * 128];
    __shared__ float u_lds[RROWS * M_SEQ * CDIM];   // [b][m][c]
    const int tid   = threadIdx.x;
    const int lcol  = tid & 127;
    const int slice = tid >> 7;
    const int b0    = blockIdx.x * RROWS;

    float a[32];
    #pragma unroll
    for (int i = 0; i < 32; ++i) a[i] = Aw[(size_t)(slice * 32 + i) * 128 + lcol];

    if (tid < RROWS * 128)
        z_lds[tid >> 7][tid & 127] = zk[(size_t)(b0 + (tid >> 7)) * 128 + (tid & 127)];
    for (int id = tid; id < CDIM * 128; id += 512) Bw_lds[id] = Bw[id];
    for (int id = tid; id < RROWS * M_SEQ * CDIM; id += 512)
        u_lds[id] = u[(size_t)b0 * M_SEQ * CDIM + id];
    __syncthreads();

    for (int m = 0; m < M_SEQ; ++m) {
        #pragma unroll
        for (int b = 0; b < RROWS; ++b) {
            const float4* z4 = (const float4*)&z_lds[b][slice * 32];
            float s = 0.f;
            #pragma unroll
            for (int i = 0; i < 8; ++i) {
                float4 zv = z4[i];
                s += a[i * 4 + 0] * zv.x + a[i * 4 + 1] * zv.y +
                     a[i * 4 + 2] * zv.z + a[i * 4 + 3] * zv.w;
            }
            part[slice][b][lcol] = s;
        }
        __syncthreads();
        {
            int b = tid >> 7, l = tid & 127;
            float v = part[0][b][l] + part[1][b][l] + part[2][b][l] + part[3][b][l];
            #pragma unroll
            for (int c = 0; c < CDIM; ++c)
                v += u_lds[(b * M_SEQ + m) * CDIM + c] * Bw_lds[c * 128 + l];
            zpred[((size_t)(b0 + b) * M_SEQ + m) * 128 + l] = v;
            z_lds[b][l] = v;
        }
        __syncthreads();
    }
}

// ---------------------------------------------------------------------------
// Decoder — VERBATIM round-3 version. 8 rows x 32 cols per 256-thread block.
// ---------------------------------------------------------------------------
__global__ __launch_bounds__(256) void decoder_kernel(
    const float* __restrict__ zpred, const float* __restrict__ Cw,
    const float* __restrict__ Cb, float* __restrict__ xpred) {
    __shared__ float C_lds[LDIM * SDIM];
    __shared__ float cb_lds[SDIM];
    const int tid = threadIdx.x;
    for (int id = tid; id < LDIM * SDIM; id += 256) C_lds[id] = Cw[id];
    if (tid < SDIM) cb_lds[tid] = Cb[tid];
    __syncthreads();

    const int col = tid & 31;
    const size_t row = (size_t)blockIdx.x * 8 + (tid >> 5);
    const float4* z4 = (const float4*)(zpred + row * LDIM);
    float s = cb_lds[col];
    #pragma unroll
    for (int i = 0; i < 32; ++i) {
        float4 zv = z4[i];
        s += zv.x * C_lds[(i * 4 + 0) * SDIM + col] + zv.y * C_lds[(i * 4 + 1) * SDIM + col] +
             zv.z * C_lds[(i * 4 + 2) * SDIM + col] + zv.w * C_lds[(i * 4 + 3) * SDIM + col];
    }
    xpred[row * SDIM + col] = s;
}

extern "C" void kernel_launch(void* const* d_in, const int* in_sizes, int n_in,
                              void* d_out, int out_size, void* d_ws, size_t ws_size,
                              hipStream_t stream) {
    const float* x_k    = (const float*)d_in[0];
    const float* u_seq  = (const float*)d_in[1];
    const float* x_next = (const float*)d_in[2];
    const float* w0 = (const float*)d_in[3];  const float* b0 = (const float*)d_in[4];
    const float* w1 = (const float*)d_in[5];  const float* b1 = (const float*)d_in[6];
    const float* w2 = (const float*)d_in[7];  const float* b2 = (const float*)d_in[8];
    const float* w3 = (const float*)d_in[9];  const float* b3 = (const float*)d_in[10];
    const float* A_w = (const float*)d_in[11];
    const float* B_w = (const float*)d_in[12];
    const float* C_w = (const float*)d_in[13];
    const float* C_b = (const float*)d_in[14];

    float* out    = (float*)d_out;
    float* z_pred = out;                                   // 2048*64*128
    float* x_pred = out + (size_t)NROWS_NEXT * LDIM;       // 2048*64*32
    float* z_tgt  = x_pred + (size_t)NROWS_NEXT * SDIM;    // 2048*64*128

    char* ws = (char*)d_ws;
    short* pw0 = (short*)(ws);                             // 32 KB
    short* pw1 = (short*)(ws + 32768);                     // 512 KB
    short* pw2 = (short*)(ws + 32768 + 524288);            // 512 KB
    short* pw3 = (short*)(ws + 32768 + 2 * 524288);        // 128 KB
    float* z_k_buf = (float*)(ws + 32768 + 2 * 524288 + 131072);  // 1 MB

    pack_all<<<(P_S3 + 255) / 256, 256, 0, stream>>>(w0, w1, w2, w3, pw0, pw1, pw2, pw3);

    encoder_kernel<<<NROWS_ALL / 64, 512, 0, stream>>>(
        x_next, x_k, pw0, pw1, pw2, pw3, b0, b1, b2, b3, z_tgt, z_k_buf);

    recurrence_kernel<<<B_TOT / RROWS, 512, 0, stream>>>(z_k_buf, u_seq, B_w, A_w, z_pred);

    decoder_kernel<<<NROWS_NEXT / 8, 256, 0, stream>>>(z_pred, C_w, C_b, x_pred);
}

// Round 8
// 657.052 us; speedup vs baseline: 1.1388x; 1.1388x over previous
//
#include <hip/hip_runtime.h>

#define B_TOT 2048
#define M_SEQ 64
#define SDIM 32
#define CDIM 8
#define LDIM 128
#define HDIM 512

#define NROWS_NEXT (B_TOT * M_SEQ)       // 131072
#define NROWS_ALL  (NROWS_NEXT + B_TOT)  // 133120

typedef short bf16x8 __attribute__((ext_vector_type(8)));
typedef float f32x4  __attribute__((ext_vector_type(4)));
typedef float f32x4v __attribute__((ext_vector_type(4)));

__device__ __forceinline__ unsigned short f2bf(float f) {
    unsigned int u = __builtin_bit_cast(unsigned int, f);
    u = u + 0x7FFFu + ((u >> 16) & 1u);   // round-to-nearest-even
    return (unsigned short)(u >> 16);
}

// XOR swizzle on LDS byte address for the bf16 h-buffer (1024B rows):
// flip bits 4-6 with row&7. Bijective, 16B-segment preserving.
// Applied to the FULL byte address (add-then-xor; R2 lesson).
__device__ __forceinline__ unsigned int swz(unsigned int byte) {
    return byte ^ (((byte >> 10) & 7u) << 4);
}

// ---------------------------------------------------------------------------
// Pack fp32 weight W[K][N] into bf16 fragment-major for 16x16x32 MFMA:
// out[((kt*(N/16) + nt)*64 + lane)*8 + j] = W[kt*32 + (lane>>4)*8 + j][nt*16 + (lane&15)]
// Single fused launch for all four weights.
// ---------------------------------------------------------------------------
__device__ __forceinline__ void pack_one16(const float* __restrict__ W, short* __restrict__ out,
                                           int e, int N) {
    int j    = e & 7;
    int lane = (e >> 3) & 63;
    int tile = e >> 9;
    int NT   = N >> 4;
    int nt   = tile % NT;
    int kt   = tile / NT;
    int k = kt * 32 + ((lane >> 4) << 3) + j;
    int n = (nt << 4) + (lane & 15);
    out[e] = (short)f2bf(W[(size_t)k * N + n]);
}

#define P_S0 16384
#define P_S1 (P_S0 + 262144)
#define P_S2 (P_S1 + 262144)
#define P_S3 (P_S2 + 65536)   // 606208 total

__global__ void pack_all(const float* __restrict__ w0, const float* __restrict__ w1,
                         const float* __restrict__ w2, const float* __restrict__ w3,
                         short* __restrict__ o0, short* __restrict__ o1,
                         short* __restrict__ o2, short* __restrict__ o3) {
    int id = blockIdx.x * 256 + threadIdx.x;
    if (id < P_S0)      pack_one16(w0, o0, id, HDIM);
    else if (id < P_S1) pack_one16(w1, o1, id - P_S0, HDIM);
    else if (id < P_S2) pack_one16(w2, o2, id - P_S1, HDIM);
    else if (id < P_S3) pack_one16(w3, o3, id - P_S2, LDIM);
}

// ---------------------------------------------------------------------------
// One MLP layer (R3-exact structure: best measured encoder, 343us).
// 8 waves; wave w owns ntiles [4w,4w+4) x all 4 mtiles. B-frags 1-deep
// prefetched; A addr = (base0 + kt*64) ^ xmask with mt*16384 immediates.
// ---------------------------------------------------------------------------
__device__ __forceinline__ void layer_lds(char* hbuf, const short* __restrict__ pw,
                                          const float* __restrict__ bias,
                                          int ktCount, int wave, int lane) {
    const int l15 = lane & 15;
    const int lhi = lane >> 4;
    const unsigned base0 = (unsigned)(l15 * 1024 + (lhi << 4));
    const unsigned xmask = ((unsigned)(l15 & 7)) << 4;

    f32x4 acc[4][4];
    #pragma unroll
    for (int mt = 0; mt < 4; ++mt)
        #pragma unroll
        for (int nt = 0; nt < 4; ++nt)
            acc[mt][nt] = (f32x4){0.f, 0.f, 0.f, 0.f};

    const short* p = pw + (wave << 11) + (lane << 3);
    bf16x8 bcur[4];
    #pragma unroll
    for (int nt = 0; nt < 4; ++nt) bcur[nt] = *(const bf16x8*)(p + (nt << 9));

    for (int kt = 0; kt < ktCount; ++kt) {
        bf16x8 bnext[4];
        if (kt + 1 < ktCount) {
            const short* pn = p + 16384;
            #pragma unroll
            for (int nt = 0; nt < 4; ++nt) bnext[nt] = *(const bf16x8*)(pn + (nt << 9));
        }
        const char* abase = hbuf + ((base0 + (unsigned)kt * 64u) ^ xmask);
        bf16x8 a[4];
        #pragma unroll
        for (int mt = 0; mt < 4; ++mt)
            a[mt] = *(const bf16x8*)(abase + mt * 16384);
        #pragma unroll
        for (int nt = 0; nt < 4; ++nt)
            #pragma unroll
            for (int mt = 0; mt < 4; ++mt)
                acc[mt][nt] = __builtin_amdgcn_mfma_f32_16x16x32_bf16(a[mt], bcur[nt], acc[mt][nt], 0, 0, 0);
        p += 16384;
        if (kt + 1 < ktCount) {
            #pragma unroll
            for (int nt = 0; nt < 4; ++nt) bcur[nt] = bnext[nt];
        }
    }
    __syncthreads();

    #pragma unroll
    for (int nt = 0; nt < 4; ++nt) {
        int colg = (wave * 4 + nt) * 16 + l15;
        float bv = bias[colg];
        #pragma unroll
        for (int mt = 0; mt < 4; ++mt) {
            #pragma unroll
            for (int r = 0; r < 4; ++r) {
                int row = mt * 16 + (lhi << 2) + r;
                float v = fmaxf(acc[mt][nt][r] + bv, 0.f);
                *(unsigned short*)(hbuf + swz((unsigned)(row * 1024 + colg * 2))) = f2bf(v);
            }
        }
    }
    __syncthreads();
}

// ---------------------------------------------------------------------------
// Fused encoder (R3-exact; only the final z store is nontemporal now).
// ---------------------------------------------------------------------------
__global__ __launch_bounds__(512, 4) void encoder_kernel(
    const float* __restrict__ x_next, const float* __restrict__ x_k,
    const short* __restrict__ pw0, const short* __restrict__ pw1,
    const short* __restrict__ pw2, const short* __restrict__ pw3,
    const float* __restrict__ b0, const float* __restrict__ b1,
    const float* __restrict__ b2, const float* __restrict__ b3,
    float* __restrict__ z_target, float* __restrict__ z_k_out) {
    __shared__ __attribute__((aligned(16))) char hbuf[64 * 1024];
    const int tid  = threadIdx.x;
    const int wave = tid >> 6;
    const int lane = tid & 63;
    const int l15  = lane & 15;
    const int lhi  = lane >> 4;
    const int r0   = blockIdx.x * 64;

    const float* xin;
    float* zout;
    bool is_tgt = (r0 < NROWS_NEXT);
    if (is_tgt) {
        xin  = x_next + (size_t)r0 * SDIM;
        zout = z_target + (size_t)r0 * LDIM;
    } else {
        xin  = x_k + (size_t)(r0 - NROWS_NEXT) * SDIM;
        zout = z_k_out + (size_t)(r0 - NROWS_NEXT) * LDIM;
    }

    // stage 64x32 fp32 -> bf16 into h cols [0,32)
    {
        int row = tid >> 3;
        int c   = (tid & 7) * 4;
        float4 v = *(const float4*)(xin + row * SDIM + c);
        uint2 pk;
        pk.x = (unsigned int)f2bf(v.x) | ((unsigned int)f2bf(v.y) << 16);
        pk.y = (unsigned int)f2bf(v.z) | ((unsigned int)f2bf(v.w) << 16);
        *(uint2*)(hbuf + swz((unsigned)(row * 1024 + c * 2))) = pk;
    }
    __syncthreads();

    layer_lds(hbuf, pw0, b0, 1, wave, lane);    // 32  -> 512, relu
    layer_lds(hbuf, pw1, b1, 16, wave, lane);   // 512 -> 512, relu
    layer_lds(hbuf, pw2, b2, 16, wave, lane);   // 512 -> 512, relu

    // layer 3: 512 -> 128, no relu; fp32 LDS staging then coalesced stores.
    {
        const unsigned base0 = (unsigned)(l15 * 1024 + (lhi << 4));
        const unsigned xmask = ((unsigned)(l15 & 7)) << 4;
        f32x4 acc[4];
        #pragma unroll
        for (int mt = 0; mt < 4; ++mt) acc[mt] = (f32x4){0.f, 0.f, 0.f, 0.f};

        const short* p = pw3 + (wave << 9) + (lane << 3);
        bf16x8 bcur = *(const bf16x8*)(p);
        for (int kt = 0; kt < 16; ++kt) {
            bf16x8 bnext;
            if (kt < 15) bnext = *(const bf16x8*)(p + 4096);
            const char* abase = hbuf + ((base0 + (unsigned)kt * 64u) ^ xmask);
            bf16x8 a[4];
            #pragma unroll
            for (int mt = 0; mt < 4; ++mt)
                a[mt] = *(const bf16x8*)(abase + mt * 16384);
            #pragma unroll
            for (int mt = 0; mt < 4; ++mt)
                acc[mt] = __builtin_amdgcn_mfma_f32_16x16x32_bf16(a[mt], bcur, acc[mt], 0, 0, 0);
            p += 4096;
            if (kt < 15) bcur = bnext;
        }
        __syncthreads();   // done reading bf16 h; reuse hbuf as [64][128] fp32

        int colg = wave * 16 + l15;
        float bv = b3[colg];
        #pragma unroll
        for (int mt = 0; mt < 4; ++mt) {
            #pragma unroll
            for (int r = 0; r < 4; ++r) {
                int row = mt * 16 + (lhi << 2) + r;
                unsigned int byte = (unsigned)(row * 512 + colg * 4);
                byte ^= ((byte >> 9) & 7u) << 4;        // fp32-tile swizzle (512B rows)
                *(float*)(hbuf + byte) = acc[mt][r] + bv;
            }
        }
        __syncthreads();

        #pragma unroll
        for (int pass = 0; pass < 4; ++pass) {
            unsigned int L = (unsigned)(pass * 512 + tid) * 16;
            unsigned int A = L ^ (((L >> 9) & 7u) << 4);
            f32x4v v = *(const f32x4v*)(hbuf + A);
            if (is_tgt) __builtin_nontemporal_store(v, (f32x4v*)(zout + (L >> 2)));
            else        *(f32x4v*)(zout + (L >> 2)) = v;
        }
    }
}

// ---------------------------------------------------------------------------
// Recurrence — VERBATIM round-3 version (known-good).
// ---------------------------------------------------------------------------
#define RROWS 4
__global__ __launch_bounds__(512) void recurrence_kernel(
    const float* __restrict__ zk, const float* __restrict__ u,
    const float* __restrict__ Bw, const float* __restrict__ Aw,
    float* __restrict__ zpred) {
    __shared__ float z_lds[RROWS][128];
    __shared__ float part[4][RROWS][128];
    __shared__ float Bw_lds[CDIM * 128];
    __shared__ float u_lds[RROWS * M_SEQ * CDIM];   // [b][m][c]
    const int tid   = threadIdx.x;
    const int lcol  = tid & 127;
    const int slice = tid >> 7;
    const int b0    = blockIdx.x * RROWS;

    float a[32];
    #pragma unroll
    for (int i = 0; i < 32; ++i) a[i] = Aw[(size_t)(slice * 32 + i) * 128 + lcol];

    if (tid < RROWS * 128)
        z_lds[tid >> 7][tid & 127] = zk[(size_t)(b0 + (tid >> 7)) * 128 + (tid & 127)];
    for (int id = tid; id < CDIM * 128; id += 512) Bw_lds[id] = Bw[id];
    for (int id = tid; id < RROWS * M_SEQ * CDIM; id += 512)
        u_lds[id] = u[(size_t)b0 * M_SEQ * CDIM + id];
    __syncthreads();

    for (int m = 0; m < M_SEQ; ++m) {
        #pragma unroll
        for (int b = 0; b < RROWS; ++b) {
            const float4* z4 = (const float4*)&z_lds[b][slice * 32];
            float s = 0.f;
            #pragma unroll
            for (int i = 0; i < 8; ++i) {
                float4 zv = z4[i];
                s += a[i * 4 + 0] * zv.x + a[i * 4 + 1] * zv.y +
                     a[i * 4 + 2] * zv.z + a[i * 4 + 3] * zv.w;
            }
            part[slice][b][lcol] = s;
        }
        __syncthreads();
        {
            int b = tid >> 7, l = tid & 127;
            float v = part[0][b][l] + part[1][b][l] + part[2][b][l] + part[3][b][l];
            #pragma unroll
            for (int c = 0; c < CDIM; ++c)
                v += u_lds[(b * M_SEQ + m) * CDIM + c] * Bw_lds[c * 128 + l];
            zpred[((size_t)(b0 + b) * M_SEQ + m) * 128 + l] = v;
            z_lds[b][l] = v;
        }
        __syncthreads();
    }
}

// ---------------------------------------------------------------------------
// Decoder x_pred = z_pred @ C_w + C_b. 64 rows/block (2048 blocks): C_w
// staged once per 64 rows -> 32MB total L2 traffic (was 256MB at 8 rows).
// ---------------------------------------------------------------------------
__global__ __launch_bounds__(256) void decoder_kernel(
    const float* __restrict__ zpred, const float* __restrict__ Cw,
    const float* __restrict__ Cb, float* __restrict__ xpred) {
    __shared__ float C_lds[LDIM * SDIM];
    __shared__ float cb_lds[SDIM];
    const int tid = threadIdx.x;
    for (int id = tid; id < LDIM * SDIM; id += 256) C_lds[id] = Cw[id];
    if (tid < SDIM) cb_lds[tid] = Cb[tid];
    __syncthreads();

    const int col = tid & 31;
    const int r8  = tid >> 5;
    const size_t rows0 = (size_t)blockIdx.x * 64;
    #pragma unroll
    for (int p = 0; p < 8; ++p) {
        size_t row = rows0 + p * 8 + r8;
        const float4* z4 = (const float4*)(zpred + row * LDIM);
        float s = cb_lds[col];
        #pragma unroll
        for (int i = 0; i < 32; ++i) {
            float4 zv = z4[i];
            s += zv.x * C_lds[(i*4+0)*SDIM + col] + zv.y * C_lds[(i*4+1)*SDIM + col] +
                 zv.z * C_lds[(i*4+2)*SDIM + col] + zv.w * C_lds[(i*4+3)*SDIM + col];
        }
        __builtin_nontemporal_store(s, xpred + row * SDIM + col);
    }
}

extern "C" void kernel_launch(void* const* d_in, const int* in_sizes, int n_in,
                              void* d_out, int out_size, void* d_ws, size_t ws_size,
                              hipStream_t stream) {
    const float* x_k    = (const float*)d_in[0];
    const float* u_seq  = (const float*)d_in[1];
    const float* x_next = (const float*)d_in[2];
    const float* w0 = (const float*)d_in[3];  const float* b0 = (const float*)d_in[4];
    const float* w1 = (const float*)d_in[5];  const float* b1 = (const float*)d_in[6];
    const float* w2 = (const float*)d_in[7];  const float* b2 = (const float*)d_in[8];
    const float* w3 = (const float*)d_in[9];  const float* b3 = (const float*)d_in[10];
    const float* A_w = (const float*)d_in[11];
    const float* B_w = (const float*)d_in[12];
    const float* C_w = (const float*)d_in[13];
    const float* C_b = (const float*)d_in[14];

    float* out    = (float*)d_out;
    float* z_pred = out;                                   // 2048*64*128
    float* x_pred = out + (size_t)NROWS_NEXT * LDIM;       // 2048*64*32
    float* z_tgt  = x_pred + (size_t)NROWS_NEXT * SDIM;    // 2048*64*128

    char* ws = (char*)d_ws;
    short* pw0 = (short*)(ws);                             // 32 KB
    short* pw1 = (short*)(ws + 32768);                     // 512 KB
    short* pw2 = (short*)(ws + 32768 + 524288);            // 512 KB
    short* pw3 = (short*)(ws + 32768 + 2 * 524288);        // 128 KB
    float* z_k_buf = (float*)(ws + 32768 + 2 * 524288 + 131072);  // 1 MB

    pack_all<<<(P_S3 + 255) / 256, 256, 0, stream>>>(w0, w1, w2, w3, pw0, pw1, pw2, pw3);

    encoder_kernel<<<NROWS_ALL / 64, 512, 0, stream>>>(
        x_next, x_k, pw0, pw1, pw2, pw3, b0, b1, b2, b3, z_tgt, z_k_buf);

    recurrence_kernel<<<B_TOT / RROWS, 512, 0, stream>>>(z_k_buf, u_seq, B_w, A_w, z_pred);

    decoder_kernel<<<NROWS_NEXT / 64, 256, 0, stream>>>(z_pred, C_w, C_b, x_pred);
}

// Round 9
// 505.127 us; speedup vs baseline: 1.4814x; 1.3008x over previous
//
#include <hip/hip_runtime.h>

#define B_TOT 2048
#define M_SEQ 64
#define SDIM 32
#define CDIM 8
#define LDIM 128
#define HDIM 512

#define NROWS_NEXT (B_TOT * M_SEQ)       // 131072
#define NROWS_ALL  (NROWS_NEXT + B_TOT)  // 133120

typedef short bf16x8 __attribute__((ext_vector_type(8)));
typedef float f32x4  __attribute__((ext_vector_type(4)));
typedef float f32x4v __attribute__((ext_vector_type(4)));

__device__ __forceinline__ unsigned short f2bf(float f) {
    unsigned int u = __builtin_bit_cast(unsigned int, f);
    u = u + 0x7FFFu + ((u >> 16) & 1u);   // round-to-nearest-even
    return (unsigned short)(u >> 16);
}

// bf16 h-buffer swizzle (1024B rows): XOR bits 4-7 with row&15 (4-bit!).
// R8 A/B evidence: 3-bit mask -> 1.31e7 bank conflicts, 4-bit -> 6.7e4.
// Applied to the FULL byte address (add-then-xor; R2 lesson).
__device__ __forceinline__ unsigned int swz(unsigned int byte) {
    return byte ^ (((byte >> 10) & 15u) << 4);
}
// fp32 staging tile swizzle (512B rows), 4-bit
__device__ __forceinline__ unsigned int swzf(unsigned int byte) {
    return byte ^ (((byte >> 9) & 15u) << 4);
}

// ---------------------------------------------------------------------------
// Pack fp32 weight W[K][N] into bf16 fragment-major for 16x16x32 MFMA:
// out[((kt*(N/16) + nt)*64 + lane)*8 + j] = W[kt*32 + (lane>>4)*8 + j][nt*16 + (lane&15)]
// Single fused launch for all four weights.
// ---------------------------------------------------------------------------
__device__ __forceinline__ void pack_one16(const float* __restrict__ W, short* __restrict__ out,
                                           int e, int N) {
    int j    = e & 7;
    int lane = (e >> 3) & 63;
    int tile = e >> 9;
    int NT   = N >> 4;
    int nt   = tile % NT;
    int kt   = tile / NT;
    int k = kt * 32 + ((lane >> 4) << 3) + j;
    int n = (nt << 4) + (lane & 15);
    out[e] = (short)f2bf(W[(size_t)k * N + n]);
}

#define P_S0 16384
#define P_S1 (P_S0 + 262144)
#define P_S2 (P_S1 + 262144)
#define P_S3 (P_S2 + 65536)   // 606208 total

__global__ void pack_all(const float* __restrict__ w0, const float* __restrict__ w1,
                         const float* __restrict__ w2, const float* __restrict__ w3,
                         short* __restrict__ o0, short* __restrict__ o1,
                         short* __restrict__ o2, short* __restrict__ o3) {
    int id = blockIdx.x * 256 + threadIdx.x;
    if (id < P_S0)      pack_one16(w0, o0, id, HDIM);
    else if (id < P_S1) pack_one16(w1, o1, id - P_S0, HDIM);
    else if (id < P_S2) pack_one16(w2, o2, id - P_S1, HDIM);
    else if (id < P_S3) pack_one16(w3, o3, id - P_S2, LDIM);
}

// ---------------------------------------------------------------------------
// One MLP layer (R3 structure, 4-bit swizzle). 8 waves; wave w owns ntiles
// [4w,4w+4) x all 4 mtiles. B-frags 1-deep prefetched.
// A addr = (base0 + kt*64) ^ (l15<<4), then mt*16384 immediates (carry-free;
// row&15 == l15 for every mt since mt*16 is a multiple of 16).
// ---------------------------------------------------------------------------
__device__ __forceinline__ void layer_lds(char* hbuf, const short* __restrict__ pw,
                                          const float* __restrict__ bias,
                                          int ktCount, int wave, int lane) {
    const int l15 = lane & 15;
    const int lhi = lane >> 4;
    const unsigned base0 = (unsigned)(l15 * 1024 + (lhi << 4));
    const unsigned xmask = ((unsigned)l15) << 4;

    f32x4 acc[4][4];
    #pragma unroll
    for (int mt = 0; mt < 4; ++mt)
        #pragma unroll
        for (int nt = 0; nt < 4; ++nt)
            acc[mt][nt] = (f32x4){0.f, 0.f, 0.f, 0.f};

    const short* p = pw + (wave << 11) + (lane << 3);
    bf16x8 bcur[4];
    #pragma unroll
    for (int nt = 0; nt < 4; ++nt) bcur[nt] = *(const bf16x8*)(p + (nt << 9));

    for (int kt = 0; kt < ktCount; ++kt) {
        bf16x8 bnext[4];
        if (kt + 1 < ktCount) {
            const short* pn = p + 16384;
            #pragma unroll
            for (int nt = 0; nt < 4; ++nt) bnext[nt] = *(const bf16x8*)(pn + (nt << 9));
        }
        const char* abase = hbuf + ((base0 + (unsigned)kt * 64u) ^ xmask);
        bf16x8 a[4];
        #pragma unroll
        for (int mt = 0; mt < 4; ++mt)
            a[mt] = *(const bf16x8*)(abase + mt * 16384);
        #pragma unroll
        for (int nt = 0; nt < 4; ++nt)
            #pragma unroll
            for (int mt = 0; mt < 4; ++mt)
                acc[mt][nt] = __builtin_amdgcn_mfma_f32_16x16x32_bf16(a[mt], bcur[nt], acc[mt][nt], 0, 0, 0);
        p += 16384;
        if (kt + 1 < ktCount) {
            #pragma unroll
            for (int nt = 0; nt < 4; ++nt) bcur[nt] = bnext[nt];
        }
    }
    __syncthreads();

    #pragma unroll
    for (int nt = 0; nt < 4; ++nt) {
        int colg = (wave * 4 + nt) * 16 + l15;
        float bv = bias[colg];
        #pragma unroll
        for (int mt = 0; mt < 4; ++mt) {
            #pragma unroll
            for (int r = 0; r < 4; ++r) {
                int row = mt * 16 + (lhi << 2) + r;
                float v = fmaxf(acc[mt][nt][r] + bv, 0.f);
                *(unsigned short*)(hbuf + swz((unsigned)(row * 1024 + colg * 2))) = f2bf(v);
            }
        }
    }
    __syncthreads();
}

// ---------------------------------------------------------------------------
// Fused encoder: 64 rows/block, 512 threads, 64KB LDS (2 blocks/CU).
// ---------------------------------------------------------------------------
__global__ __launch_bounds__(512, 4) void encoder_kernel(
    const float* __restrict__ x_next, const float* __restrict__ x_k,
    const short* __restrict__ pw0, const short* __restrict__ pw1,
    const short* __restrict__ pw2, const short* __restrict__ pw3,
    const float* __restrict__ b0, const float* __restrict__ b1,
    const float* __restrict__ b2, const float* __restrict__ b3,
    float* __restrict__ z_target, float* __restrict__ z_k_out) {
    __shared__ __attribute__((aligned(16))) char hbuf[64 * 1024];
    const int tid  = threadIdx.x;
    const int wave = tid >> 6;
    const int lane = tid & 63;
    const int l15  = lane & 15;
    const int lhi  = lane >> 4;
    const int r0   = blockIdx.x * 64;

    const float* xin;
    float* zout;
    bool is_tgt = (r0 < NROWS_NEXT);
    if (is_tgt) {
        xin  = x_next + (size_t)r0 * SDIM;
        zout = z_target + (size_t)r0 * LDIM;
    } else {
        xin  = x_k + (size_t)(r0 - NROWS_NEXT) * SDIM;
        zout = z_k_out + (size_t)(r0 - NROWS_NEXT) * LDIM;
    }

    // stage 64x32 fp32 -> bf16 into h cols [0,32)
    {
        int row = tid >> 3;
        int c   = (tid & 7) * 4;
        float4 v = *(const float4*)(xin + row * SDIM + c);
        uint2 pk;
        pk.x = (unsigned int)f2bf(v.x) | ((unsigned int)f2bf(v.y) << 16);
        pk.y = (unsigned int)f2bf(v.z) | ((unsigned int)f2bf(v.w) << 16);
        *(uint2*)(hbuf + swz((unsigned)(row * 1024 + c * 2))) = pk;
    }
    __syncthreads();

    layer_lds(hbuf, pw0, b0, 1, wave, lane);    // 32  -> 512, relu
    layer_lds(hbuf, pw1, b1, 16, wave, lane);   // 512 -> 512, relu
    layer_lds(hbuf, pw2, b2, 16, wave, lane);   // 512 -> 512, relu

    // layer 3: 512 -> 128, no relu; fp32 LDS staging then coalesced stores.
    {
        const unsigned base0 = (unsigned)(l15 * 1024 + (lhi << 4));
        const unsigned xmask = ((unsigned)l15) << 4;
        f32x4 acc[4];
        #pragma unroll
        for (int mt = 0; mt < 4; ++mt) acc[mt] = (f32x4){0.f, 0.f, 0.f, 0.f};

        const short* p = pw3 + (wave << 9) + (lane << 3);
        bf16x8 bcur = *(const bf16x8*)(p);
        for (int kt = 0; kt < 16; ++kt) {
            bf16x8 bnext;
            if (kt < 15) bnext = *(const bf16x8*)(p + 4096);
            const char* abase = hbuf + ((base0 + (unsigned)kt * 64u) ^ xmask);
            bf16x8 a[4];
            #pragma unroll
            for (int mt = 0; mt < 4; ++mt)
                a[mt] = *(const bf16x8*)(abase + mt * 16384);
            #pragma unroll
            for (int mt = 0; mt < 4; ++mt)
                acc[mt] = __builtin_amdgcn_mfma_f32_16x16x32_bf16(a[mt], bcur, acc[mt], 0, 0, 0);
            p += 4096;
            if (kt < 15) bcur = bnext;
        }
        __syncthreads();   // done reading bf16 h; reuse hbuf as [64][128] fp32

        int colg = wave * 16 + l15;
        float bv = b3[colg];
        #pragma unroll
        for (int mt = 0; mt < 4; ++mt) {
            #pragma unroll
            for (int r = 0; r < 4; ++r) {
                int row = mt * 16 + (lhi << 2) + r;
                *(float*)(hbuf + swzf((unsigned)(row * 512 + colg * 4))) = acc[mt][r] + bv;
            }
        }
        __syncthreads();

        #pragma unroll
        for (int pass = 0; pass < 4; ++pass) {
            unsigned int L = (unsigned)(pass * 512 + tid) * 16;
            f32x4v v = *(const f32x4v*)(hbuf + swzf(L));
            if (is_tgt) __builtin_nontemporal_store(v, (f32x4v*)(zout + (L >> 2)));
            else        *(f32x4v*)(zout + (L >> 2)) = v;
        }
    }
}

// ---------------------------------------------------------------------------
// Recurrence — VERBATIM round-3 version (known-good).
// ---------------------------------------------------------------------------
#define RROWS 4
__global__ __launch_bounds__(512) void recurrence_kernel(
    const float* __restrict__ zk, const float* __restrict__ u,
    const float* __restrict__ Bw, const float* __restrict__ Aw,
    float* __restrict__ zpred) {
    __shared__ float z_lds[RROWS][128];
    __shared__ float part[4][RROWS][128];
    __shared__ float Bw_lds[CDIM * 128];
    __shared__ float u_lds[RROWS * M_SEQ * CDIM];   // [b][m][c]
    const int tid   = threadIdx.x;
    const int lcol  = tid & 127;
    const int slice = tid >> 7;
    const int b0    = blockIdx.x * RROWS;

    float a[32];
    #pragma unroll
    for (int i = 0; i < 32; ++i) a[i] = Aw[(size_t)(slice * 32 + i) * 128 + lcol];

    if (tid < RROWS * 128)
        z_lds[tid >> 7][tid & 127] = zk[(size_t)(b0 + (tid >> 7)) * 128 + (tid & 127)];
    for (int id = tid; id < CDIM * 128; id += 512) Bw_lds[id] = Bw[id];
    for (int id = tid; id < RROWS * M_SEQ * CDIM; id += 512)
        u_lds[id] = u[(size_t)b0 * M_SEQ * CDIM + id];
    __syncthreads();

    for (int m = 0; m < M_SEQ; ++m) {
        #pragma unroll
        for (int b = 0; b < RROWS; ++b) {
            const float4* z4 = (const float4*)&z_lds[b][slice * 32];
            float s = 0.f;
            #pragma unroll
            for (int i = 0; i < 8; ++i) {
                float4 zv = z4[i];
                s += a[i * 4 + 0] * zv.x + a[i * 4 + 1] * zv.y +
                     a[i * 4 + 2] * zv.z + a[i * 4 + 3] * zv.w;
            }
            part[slice][b][lcol] = s;
        }
        __syncthreads();
        {
            int b = tid >> 7, l = tid & 127;
            float v = part[0][b][l] + part[1][b][l] + part[2][b][l] + part[3][b][l];
            #pragma unroll
            for (int c = 0; c < CDIM; ++c)
                v += u_lds[(b * M_SEQ + m) * CDIM + c] * Bw_lds[c * 128 + l];
            zpred[((size_t)(b0 + b) * M_SEQ + m) * 128 + l] = v;
            z_lds[b][l] = v;
        }
        __syncthreads();
    }
}

// ---------------------------------------------------------------------------
// Decoder — VERBATIM round-3 version (8 rows x 32 cols per 256-thread block;
// the 64-row variant costs +150us: R5/R6/R8 ledger).
// ---------------------------------------------------------------------------
__global__ __launch_bounds__(256) void decoder_kernel(
    const float* __restrict__ zpred, const float* __restrict__ Cw,
    const float* __restrict__ Cb, float* __restrict__ xpred) {
    __shared__ float C_lds[LDIM * SDIM];
    __shared__ float cb_lds[SDIM];
    const int tid = threadIdx.x;
    for (int id = tid; id < LDIM * SDIM; id += 256) C_lds[id] = Cw[id];
    if (tid < SDIM) cb_lds[tid] = Cb[tid];
    __syncthreads();

    const int col = tid & 31;
    const size_t row = (size_t)blockIdx.x * 8 + (tid >> 5);
    const float4* z4 = (const float4*)(zpred + row * LDIM);
    float s = cb_lds[col];
    #pragma unroll
    for (int i = 0; i < 32; ++i) {
        float4 zv = z4[i];
        s += zv.x * C_lds[(i * 4 + 0) * SDIM + col] + zv.y * C_lds[(i * 4 + 1) * SDIM + col] +
             zv.z * C_lds[(i * 4 + 2) * SDIM + col] + zv.w * C_lds[(i * 4 + 3) * SDIM + col];
    }
    xpred[row * SDIM + col] = s;
}

extern "C" void kernel_launch(void* const* d_in, const int* in_sizes, int n_in,
                              void* d_out, int out_size, void* d_ws, size_t ws_size,
                              hipStream_t stream) {
    const float* x_k    = (const float*)d_in[0];
    const float* u_seq  = (const float*)d_in[1];
    const float* x_next = (const float*)d_in[2];
    const float* w0 = (const float*)d_in[3];  const float* b0 = (const float*)d_in[4];
    const float* w1 = (const float*)d_in[5];  const float* b1 = (const float*)d_in[6];
    const float* w2 = (const float*)d_in[7];  const float* b2 = (const float*)d_in[8];
    const float* w3 = (const float*)d_in[9];  const float* b3 = (const float*)d_in[10];
    const float* A_w = (const float*)d_in[11];
    const float* B_w = (const float*)d_in[12];
    const float* C_w = (const float*)d_in[13];
    const float* C_b = (const float*)d_in[14];

    float* out    = (float*)d_out;
    float* z_pred = out;                                   // 2048*64*128
    float* x_pred = out + (size_t)NROWS_NEXT * LDIM;       // 2048*64*32
    float* z_tgt  = x_pred + (size_t)NROWS_NEXT * SDIM;    // 2048*64*128

    char* ws = (char*)d_ws;
    short* pw0 = (short*)(ws);                             // 32 KB
    short* pw1 = (short*)(ws + 32768);                     // 512 KB
    short* pw2 = (short*)(ws + 32768 + 524288);            // 512 KB
    short* pw3 = (short*)(ws + 32768 + 2 * 524288);        // 128 KB
    float* z_k_buf = (float*)(ws + 32768 + 2 * 524288 + 131072);  // 1 MB

    pack_all<<<(P_S3 + 255) / 256, 256, 0, stream>>>(w0, w1, w2, w3, pw0, pw1, pw2, pw3);

    encoder_kernel<<<NROWS_ALL / 64, 512, 0, stream>>>(
        x_next, x_k, pw0, pw1, pw2, pw3, b0, b1, b2, b3, z_tgt, z_k_buf);

    recurrence_kernel<<<B_TOT / RROWS, 512, 0, stream>>>(z_k_buf, u_seq, B_w, A_w, z_pred);

    decoder_kernel<<<NROWS_NEXT / 8, 256, 0, stream>>>(z_pred, C_w, C_b, x_pred);
}